// Round 10
// baseline (251.957 us; speedup 1.0000x reference)
//
#include <hip/hip_runtime.h>
#include <hip/hip_bf16.h>

// Problem constants (reference: B=2, T=2048, C=2048, NH=16, NKV=4, HD=128, GATE_CH=12)
#define BB   2
#define TT   2048
#define CC   2048
#define NHq  16
#define NKVq 4
#define HDq  128
#define ROWS (BB*TT)          // 4096
#define NQKV (NHq*HDq + 2*NKVq*HDq)  // 3072

using bf16 = __hip_bfloat16;
using short8  = __attribute__((ext_vector_type(8))) short;
using short4v = __attribute__((ext_vector_type(4))) short;
using f32x4   = __attribute__((ext_vector_type(4))) float;

#define MFMA16(a,b,c) __builtin_amdgcn_mfma_f32_16x16x32_bf16((a),(b),(c),0,0,0)

// async global->LDS, 16B per lane. LDS dest must be wave-uniform-base + lane*16.
__device__ __forceinline__ void gll16(const bf16* g, void* l) {
    __builtin_amdgcn_global_load_lds((const __attribute__((address_space(1))) void*)g,
                                     (__attribute__((address_space(3))) void*)l,
                                     16, 0, 0);
}

// ---------------- fused cast: all fp32 inputs -> contiguous bf16 ws regions ----------------
// dst layout: [xb 8388608 | wq 4194304 | wk 1048576 | wv 1048576 | wproj 4194304]
// Wq/Wk rows are chunk-swapped (32-chunks 1<->2 within each 128-row head) so the
// fused RoPE epilogue in gemm_qkv has both rotation partners register-local.
__global__ void cast_all(const float* __restrict__ x,  const float* __restrict__ wq,
                         const float* __restrict__ wk, const float* __restrict__ wv,
                         const float* __restrict__ wp, bf16* __restrict__ dst) {
    long e = ((long)blockIdx.x * 256 + threadIdx.x) * 4;
    const float* src; long off; long dsto = e; int permute = 0; long rbase = 0;
    if (e < 8388608L)       { src = x;  off = e; }
    else if (e < 12582912L) { src = wq; off = e - 8388608L;  permute = 1; rbase = 8388608L; }
    else if (e < 13631488L) { src = wk; off = e - 12582912L; permute = 1; rbase = 12582912L; }
    else if (e < 14680064L) { src = wv; off = e - 13631488L; }
    else                    { src = wp; off = e - 14680064L; }
    if (permute) {
        long row = off >> 11, col = off & 2047;
        int hl = (int)(row & 127), c = hl >> 5;
        int hl2 = (c == 1) ? hl + 32 : (c == 2) ? hl - 32 : hl;
        dsto = rbase + ((row & ~127L) | hl2) * 2048 + col;
    }
    float4 v = *reinterpret_cast<const float4*>(src + off);
    ushort4 o;
    o.x = __bfloat16_as_ushort(__float2bfloat16(v.x));
    o.y = __bfloat16_as_ushort(__float2bfloat16(v.y));
    o.z = __bfloat16_as_ushort(__float2bfloat16(v.z));
    o.w = __bfloat16_as_ushort(__float2bfloat16(v.w));
    *reinterpret_cast<ushort4*>(dst + dsto) = o;
}

// ---------------- prep: packed cos/sin table ----------------
__global__ void prep_cs(const float* __restrict__ cosb, const float* __restrict__ sinb,
                        float4* __restrict__ cs) {
    int id = blockIdx.x * 256 + threadIdx.x;       // t*32 + i, 65536 total
    int t = id >> 5, i = id & 31;
    int d0 = (i >> 4) * 32 + (i & 15);
    int d1 = d0 + 16;
    cs[id] = float4{cosb[t * 64 + d0], sinb[t * 64 + d0],
                    cosb[t * 64 + d1], sinb[t * 64 + d1]};
}

// ---------------- bf16 MFMA GEMM (m97, natural block order), used for out-proj ----------------
template<int OUT_F32>
__global__ __launch_bounds__(256) void gemm_bt(const bf16* __restrict__ A,
                                               const bf16* __restrict__ B,
                                               void* __restrict__ Cp,
                                               int M, int N, int K) {
    const int bm = blockIdx.x * 128;
    const int bn = blockIdx.y * 128;
    const int tid = threadIdx.x;
    const int lane = tid & 63;
    const int w = tid >> 6;
    const int wr = w >> 1, wc = w & 1;   // 2x2 waves of 64x64

    __shared__ __align__(16) bf16 As[128 * 32];
    __shared__ __align__(16) bf16 Bs[128 * 32];

    f32x4 acc[4][4];
#pragma unroll
    for (int i = 0; i < 4; ++i)
#pragma unroll
        for (int j = 0; j < 4; ++j) acc[i][j] = f32x4{0.f, 0.f, 0.f, 0.f};

    const int srow = tid >> 2;
    const int scol = (tid & 3) * 8;

    for (int k0 = 0; k0 < K; k0 += 32) {
        __syncthreads();
#pragma unroll
        for (int p = 0; p < 2; ++p) {
            gll16(&A[(size_t)(bm + p * 64 + srow) * K + k0 + scol], (char*)As + p * 4096 + tid * 16);
            gll16(&B[(size_t)(bn + p * 64 + srow) * K + k0 + scol], (char*)Bs + p * 4096 + tid * 16);
        }
        __syncthreads();

        const int fr = lane & 15;
        const int kq = (lane >> 4) * 8;
        short8 af[4], bfr[4];
#pragma unroll
        for (int m = 0; m < 4; ++m)
            af[m] = *reinterpret_cast<const short8*>(&As[(wr * 64 + m * 16 + fr) * 32 + kq]);
#pragma unroll
        for (int n = 0; n < 4; ++n)
            bfr[n] = *reinterpret_cast<const short8*>(&Bs[(wc * 64 + n * 16 + fr) * 32 + kq]);
#pragma unroll
        for (int m = 0; m < 4; ++m)
#pragma unroll
            for (int n = 0; n < 4; ++n)
                acc[m][n] = MFMA16(af[m], bfr[n], acc[m][n]);
    }

    const int cr = (lane >> 4) * 4;
    const int cc = lane & 15;
#pragma unroll
    for (int m = 0; m < 4; ++m)
#pragma unroll
        for (int n = 0; n < 4; ++n) {
            int row = bm + wr * 64 + m * 16 + cr;
            int col = bn + wc * 64 + n * 16 + cc;
#pragma unroll
            for (int j = 0; j < 4; ++j) {
                float v = acc[m][n][j];
                if (OUT_F32) ((float*)Cp)[(size_t)(row + j) * N + col] = v;
                else         ((bf16*)Cp)[(size_t)(row + j) * N + col] = __float2bfloat16(v);
            }
        }
}

// ---------------- qkv GEMM v4: 256x256 tile, ring-of-4 BK=32, 3-deep counted pipeline ----------------
// 4 LDS slots; staging runs 3 steps ahead (12 loads in flight/wave); per step:
// {issue 4 gll16 for s+3 -> vmcnt(12) -> barrier -> 12 ds_read + 32 MFMA (setprio) -> barrier}.
// Tail: 3 peeled steps with vmcnt(8)/(4)/(0). BK=32 row stride 64B = bank-benign (no swizzle).
// Wave-tile 128x64 (2x4 waves). Fused RoPE/RMSNorm/gate epilogue (chunk-swapped W).
__global__ __launch_bounds__(512, 2) void gemm_qkv(const bf16* __restrict__ A,
                                                   const bf16* __restrict__ B,
                                                   bf16* __restrict__ qkv,
                                                   const float* __restrict__ x,
                                                   const float* __restrict__ ve,
                                                   const float4* __restrict__ csTab,
                                                   const float* __restrict__ Wgate) {
    const int K = CC;                 // 2048
    const int NT = K / 32;            // 64 K-steps
    const int bm = blockIdx.x * 256;
    const int bn = blockIdx.y * 256;
    const int tid = threadIdx.x;      // 0..511
    const int lane = tid & 63;
    const int w = tid >> 6;           // 0..7
    const int wm = w >> 2;            // 0..1 (M)
    const int wn = w & 3;             // 0..3 (N)

    __shared__ __align__(16) bf16 As[4][256 * 32];   // 64 KB ring
    __shared__ __align__(16) bf16 Bs[4][256 * 32];   // 64 KB ring
    __shared__ float exch[4][2][128];                // 4 KB RMS partials
    __shared__ float gate_s[2][256];                 // 2 KB v-gate

    const bool isv = (bn >= 2560);
    if (isv) {
        // gate 12-dot for both kv-heads of this block; hides under staging
        const int r = tid & 255, kv = tid >> 8;
        const int kvh_w = ((bn - 2560) >> 7) + kv;
        float g = 0.f;
#pragma unroll
        for (int c = 0; c < 12; ++c) g += x[(size_t)(bm + r) * CC + c] * Wgate[kvh_w * 12 + c];
        gate_s[kv][r] = 3.0f / (1.0f + __expf(-g));
    }
    __builtin_amdgcn_sched_barrier(0);   // keep gate's loads/waits above the pipeline

    f32x4 acc[8][4];
#pragma unroll
    for (int i = 0; i < 8; ++i)
#pragma unroll
        for (int j = 0; j < 4; ++j) acc[i][j] = f32x4{0.f, 0.f, 0.f, 0.f};

    const int fr = lane & 15;
    const int kq = lane >> 4;         // 16B chunk within 32-col step

    // stage step s into slot s&3 (4 gll16/thread: 2 A + 2 B)
    auto stage_step = [&](int s) {
        const int slot = s & 3;
        const int k0 = s * 32;
        const int row0 = tid >> 2;
        const int ch = tid & 3;
#pragma unroll
        for (int i = 0; i < 2; ++i)
            gll16(&A[(size_t)(bm + i * 128 + row0) * K + k0 + ch * 8],
                  (char*)As[slot] + i * 8192 + tid * 16);
#pragma unroll
        for (int i = 0; i < 2; ++i)
            gll16(&B[(size_t)(bn + i * 128 + row0) * K + k0 + ch * 8],
                  (char*)Bs[slot] + i * 8192 + tid * 16);
    };

    // compute one K-step from slot: 12 ds_read_b128 + 32 MFMA
    auto compute_step = [&](int slot) {
        const char* Ab = (const char*)As[slot];
        const char* Bb = (const char*)Bs[slot];
        short8 bfrag[4];
#pragma unroll
        for (int nf = 0; nf < 4; ++nf) {
            int row = wn * 64 + nf * 16 + fr;
            bfrag[nf] = *reinterpret_cast<const short8*>(Bb + row * 64 + kq * 16);
        }
        __builtin_amdgcn_s_setprio(1);
#pragma unroll
        for (int mf = 0; mf < 8; ++mf) {
            int row = wm * 128 + mf * 16 + fr;
            short8 afrag = *reinterpret_cast<const short8*>(Ab + row * 64 + kq * 16);
#pragma unroll
            for (int nf = 0; nf < 4; ++nf)
                acc[mf][nf] = MFMA16(afrag, bfrag[nf], acc[mf][nf]);
        }
        __builtin_amdgcn_s_setprio(0);
    };

    // ---- prologue: 3 steps in flight ----
    stage_step(0); stage_step(1); stage_step(2);

    // ---- main loop: issue s+3, counted wait for s (12 = 3 steps x 4 loads in flight) ----
    for (int s = 0; s < NT - 3; ++s) {
        stage_step(s + 3);
        asm volatile("s_waitcnt vmcnt(12)" ::: "memory");
        __builtin_amdgcn_sched_barrier(0);
        __builtin_amdgcn_s_barrier();          // slot s&3 ready block-wide
        __builtin_amdgcn_sched_barrier(0);
        compute_step(s & 3);
        __builtin_amdgcn_sched_barrier(0);
        __builtin_amdgcn_s_barrier();          // all reads of slot s&3 done (it's restaged at s+1)
    }
    // ---- peeled tail: s = NT-3, NT-2, NT-1 (no staging; drain 8 -> 4 -> 0) ----
    asm volatile("s_waitcnt vmcnt(8)" ::: "memory");
    __builtin_amdgcn_sched_barrier(0);
    __builtin_amdgcn_s_barrier();
    __builtin_amdgcn_sched_barrier(0);
    compute_step((NT - 3) & 3);
    __builtin_amdgcn_s_barrier();
    asm volatile("s_waitcnt vmcnt(4)" ::: "memory");
    __builtin_amdgcn_sched_barrier(0);
    __builtin_amdgcn_s_barrier();
    __builtin_amdgcn_sched_barrier(0);
    compute_step((NT - 2) & 3);
    __builtin_amdgcn_s_barrier();
    asm volatile("s_waitcnt vmcnt(0)" ::: "memory");
    __builtin_amdgcn_sched_barrier(0);
    __builtin_amdgcn_s_barrier();
    __builtin_amdgcn_sched_barrier(0);
    compute_step((NT - 1) & 3);
    __syncthreads();   // full drain before epilogue LDS reuse

    // ---- fused epilogue ----
    const int hi = lane >> 4;
    if (!isv) {
        // RoPE + RMSNorm + *1.2. Wave covers one 64-col half-head (chunk-swapped layout):
        // frags 0,1 = x1 (d = p*16+fr), frags 2,3 = x2 (d+64). Partner half = wave wn^1.
        const int half = wn & 1;
        const int headb = bn + (wn >> 1) * 128;
        const int ci = half * 16 + fr;
#pragma unroll
        for (int mf = 0; mf < 8; ++mf)
#pragma unroll
            for (int j = 0; j < 4; ++j) {
                const int lr = mf * 16 + hi * 4 + j;
                const int row = bm + wm * 128 + lr;
                const int t_ = row & (TT - 1);
                float4 cs = csTab[t_ * 32 + ci];
                float ss = 0.f;
                {
                    float x1 = acc[mf][0][j], x2 = acc[mf][2][j];
                    float r1 =  x1 * cs.x + x2 * cs.y;
                    float r2 = -x1 * cs.y + x2 * cs.x;
                    ss += r1 * r1 + r2 * r2;
                    acc[mf][0][j] = r1; acc[mf][2][j] = r2;
                }
                {
                    float x1 = acc[mf][1][j], x2 = acc[mf][3][j];
                    float r1 =  x1 * cs.z + x2 * cs.w;
                    float r2 = -x1 * cs.w + x2 * cs.z;
                    ss += r1 * r1 + r2 * r2;
                    acc[mf][1][j] = r1; acc[mf][3][j] = r2;
                }
#pragma unroll
                for (int mm = 1; mm < 16; mm <<= 1) ss += __shfl_xor(ss, mm);
                if (fr == 0) exch[wn][wm][lr] = ss;
            }
        __syncthreads();
#pragma unroll
        for (int mf = 0; mf < 8; ++mf)
#pragma unroll
            for (int j = 0; j < 4; ++j) {
                const int lr = mf * 16 + hi * 4 + j;
                const int row = bm + wm * 128 + lr;
                float sst = exch[wn][wm][lr] + exch[wn ^ 1][wm][lr];
                float sc = rsqrtf(sst * (1.0f / 128.0f) + 1e-6f) * 1.2f;
                bf16* o = qkv + (size_t)row * NQKV + headb;
#pragma unroll
                for (int p = 0; p < 2; ++p) {
                    const int d = half * 32 + p * 16 + fr;
                    o[d]      = __float2bfloat16(acc[mf][p][j] * sc);
                    o[d + 64] = __float2bfloat16(acc[mf][p + 2][j] * sc);
                }
            }
    } else {
        // v: gate + ve add (gate from LDS)
        const int kv = wn >> 1;
        const int kvh_w = ((bn - 2560) >> 7) + kv;
#pragma unroll
        for (int mf = 0; mf < 8; ++mf)
#pragma unroll
            for (int j = 0; j < 4; ++j) {
                const int lr = mf * 16 + hi * 4 + j;
                const int brow = wm * 128 + lr;
                const int row = bm + brow;
                const float g = gate_s[kv][brow];
                bf16* o = qkv + (size_t)row * NQKV + bn + kv * 128 + (wn & 1) * 64;
                const float* vep = ve + (size_t)row * 512 + kvh_w * 128 + (wn & 1) * 64;
#pragma unroll
                for (int nf = 0; nf < 4; ++nf) {
                    const int d = nf * 16 + fr;
                    o[d] = __float2bfloat16(acc[mf][nf][j] + g * vep[d]);
                }
            }
    }
}

// ---------------- MFMA flash attention v5 (unchanged) ----------------
__global__ __launch_bounds__(256, 2) void attn_mfma(const bf16* __restrict__ qkv,
                                                    bf16* __restrict__ y,
                                                    const int* __restrict__ winp) {
    const int bid = blockIdx.x;
    const int group = bid >> 8, idx = bid & 255;
    const int bh = idx >> 3, jj = idx & 7;
    const int qt = group ? jj : (15 - jj);
    const int h = bh & 15, b = bh >> 4;
    const int t0 = qt * 128;
    const int kvh = h >> 2;
    const int tid = threadIdx.x;
    const int lane = tid & 63;
    const int w = tid >> 6;
    const int window = winp[0];

    __shared__ __align__(16) bf16 Ks[2][64 * 128];
    __shared__ __align__(16) bf16 Vt[128 * 64];
    __shared__ __align__(16) bf16 Ps[4][32 * 64];

    const int fr = lane & 15;
    const int kq = (lane >> 4) * 8;
    const int hi = lane >> 4;

    short8 qf[2][4];
#pragma unroll
    for (int mi = 0; mi < 2; ++mi) {
        const bf16* qp = qkv + ((size_t)(b * TT) + t0 + w * 32 + mi * 16 + fr) * NQKV + h * HDq;
#pragma unroll
        for (int c = 0; c < 4; ++c)
            qf[mi][c] = *reinterpret_cast<const short8*>(&qp[c * 32 + kq]);
    }

    f32x4 acc[2][8];
#pragma unroll
    for (int mi = 0; mi < 2; ++mi)
#pragma unroll
        for (int n = 0; n < 8; ++n) acc[mi][n] = f32x4{0.f, 0.f, 0.f, 0.f};
    float m2[2][4], lrow[2][4];
#pragma unroll
    for (int mi = 0; mi < 2; ++mi)
#pragma unroll
        for (int j = 0; j < 4; ++j) { m2[mi][j] = -1e30f; lrow[mi][j] = 0.f; }

    int s_lo = t0 - window; if (s_lo < 0) s_lo = 0; s_lo &= ~63;
    const int s_end = t0 + 128;

    const bf16* Kg = qkv + (size_t)b * TT * NQKV + 2048 + kvh * HDq;
    const bf16* Vg = Kg + 512;

    const int str = tid >> 4;
    const int sti = tid & 15;
    const int vf  = tid & 15;
    const int vdc = (tid >> 4) * 8;
    const float scl2 = 0.08838834764831845f * 1.4426950408889634f;
    const float THR2 = 11.54f;

    short8 vr[4];

#pragma unroll
    for (int p = 0; p < 4; ++p) {
        int row = p * 16 + str;
        int c16 = sti ^ (row & 7);
        gll16(&Kg[(size_t)(s_lo + row) * NQKV + c16 * 8], (char*)Ks + p * 4096 + tid * 16);
    }
#pragma unroll
    for (int i = 0; i < 4; ++i)
        vr[i] = *reinterpret_cast<const short8*>(&Vg[(size_t)(s_lo + 16 * i + vf) * NQKV + vdc]);
#pragma unroll
    for (int j = 0; j < 8; ++j) {
        short4v col;
        col[0] = vr[0][j]; col[1] = vr[1][j]; col[2] = vr[2][j]; col[3] = vr[3][j];
        *reinterpret_cast<short4v*>((char*)Vt + (vdc + j) * 128 + ((8 * vf) ^ (j << 4))) = col;
    }
    __syncthreads();

    int cur = 0;
    for (int sk = s_lo; sk < s_end; sk += 64) {
        const bool hn = (sk + 64 < s_end);
        if (hn) {
#pragma unroll
            for (int p = 0; p < 4; ++p) {
                int row = p * 16 + str;
                int c16 = sti ^ (row & 7);
                gll16(&Kg[(size_t)(sk + 64 + row) * NQKV + c16 * 8],
                      (char*)Ks + (cur ^ 1) * 16384 + p * 4096 + tid * 16);
            }
#pragma unroll
            for (int i = 0; i < 4; ++i)
                vr[i] = *reinterpret_cast<const short8*>(&Vg[(size_t)(sk + 64 + 16 * i + vf) * NQKV + vdc]);
        }

        f32x4 S[2][4];
#pragma unroll
        for (int mi = 0; mi < 2; ++mi)
#pragma unroll
            for (int n = 0; n < 4; ++n) S[mi][n] = f32x4{0.f, 0.f, 0.f, 0.f};
        __builtin_amdgcn_s_setprio(1);
#pragma unroll
        for (int n = 0; n < 4; ++n) {
            int rb = n * 16 + fr;
#pragma unroll
            for (int c = 0; c < 4; ++c) {
                int colb = c * 64 + kq * 2;
                short8 kf = *reinterpret_cast<const short8*>(
                    (const char*)Ks + cur * 16384 + rb * 256 + (colb ^ ((rb & 7) << 4)));
                S[0][n] = MFMA16(qf[0][c], kf, S[0][n]);
                S[1][n] = MFMA16(qf[1][c], kf, S[1][n]);
            }
        }
        __builtin_amdgcn_s_setprio(0);

        const int rw0 = t0 + w * 32;
        const bool interior = (sk + 63 <= rw0) && (rw0 + 31 - sk <= window);
#pragma unroll
        for (int mi = 0; mi < 2; ++mi) {
#pragma unroll
            for (int j = 0; j < 4; ++j) {
                const int rl = hi * 4 + j;
                float s0, s1, s2, s3;
                if (interior) {
                    s0 = S[mi][0][j] * scl2; s1 = S[mi][1][j] * scl2;
                    s2 = S[mi][2][j] * scl2; s3 = S[mi][3][j] * scl2;
                } else {
                    const int r = rw0 + mi * 16 + rl;
                    int c0 = sk + fr, c1 = c0 + 16, c2 = c0 + 32, c3 = c0 + 48;
                    s0 = (c0 <= r && r - c0 <= window) ? S[mi][0][j] * scl2 : -1e30f;
                    s1 = (c1 <= r && r - c1 <= window) ? S[mi][1][j] * scl2 : -1e30f;
                    s2 = (c2 <= r && r - c2 <= window) ? S[mi][2][j] * scl2 : -1e30f;
                    s3 = (c3 <= r && r - c3 <= window) ? S[mi][3][j] * scl2 : -1e30f;
                }
                float pm = fmaxf(fmaxf(s0, s1), fmaxf(s2, s3));
                if (!__all(pm <= m2[mi][j] + THR2)) {
                    float pr = pm;
#pragma unroll
                    for (int mm = 1; mm < 16; mm <<= 1) pr = fmaxf(pr, __shfl_xor(pr, mm));
                    float nm = fmaxf(m2[mi][j], pr);
                    float corr = exp2f(m2[mi][j] - nm);
                    m2[mi][j] = nm;
                    lrow[mi][j] *= corr;
#pragma unroll
                    for (int n = 0; n < 8; ++n) acc[mi][n][j] *= corr;
                }
                float p0 = exp2f(s0 - m2[mi][j]);
                float p1 = exp2f(s1 - m2[mi][j]);
                float p2 = exp2f(s2 - m2[mi][j]);
                float p3 = exp2f(s3 - m2[mi][j]);
                if (!interior) {
                    p0 = (s0 > -1e29f) ? p0 : 0.f;
                    p1 = (s1 > -1e29f) ? p1 : 0.f;
                    p2 = (s2 > -1e29f) ? p2 : 0.f;
                    p3 = (s3 > -1e29f) ? p3 : 0.f;
                }
                lrow[mi][j] += (p0 + p1) + (p2 + p3);
                short4v pk;
                pk[0] = (short)__bfloat16_as_ushort(__float2bfloat16(p0));
                pk[1] = (short)__bfloat16_as_ushort(__float2bfloat16(p1));
                pk[2] = (short)__bfloat16_as_ushort(__float2bfloat16(p2));
                pk[3] = (short)__bfloat16_as_ushort(__float2bfloat16(p3));
                const int prow = mi * 16 + rl;
                *reinterpret_cast<short4v*>(
                    (char*)Ps + w * 4096 + prow * 128 + ((8 * fr) ^ ((prow & 7) << 4))) = pk;
            }
        }

        __builtin_amdgcn_s_setprio(1);
#pragma unroll
        for (int c2 = 0; c2 < 2; ++c2) {
            short8 pa0 = *reinterpret_cast<const short8*>(
                (char*)Ps + w * 4096 + fr * 128 + ((c2 * 64 + hi * 16) ^ ((fr & 7) << 4)));
            short8 pa1 = *reinterpret_cast<const short8*>(
                (char*)Ps + w * 4096 + (16 + fr) * 128 + ((c2 * 64 + hi * 16) ^ ((fr & 7) << 4)));
#pragma unroll
            for (int n = 0; n < 8; ++n) {
                short8 vb = *reinterpret_cast<const short8*>(
                    (char*)Vt + (n * 16 + fr) * 128 + ((c2 * 64 + hi * 16) ^ ((fr & 7) << 4)));
                acc[0][n] = MFMA16(pa0, vb, acc[0][n]);
                acc[1][n] = MFMA16(pa1, vb, acc[1][n]);
            }
        }
        __builtin_amdgcn_s_setprio(0);

        __syncthreads();
        if (hn) {
#pragma unroll
            for (int j = 0; j < 8; ++j) {
                short4v col;
                col[0] = vr[0][j]; col[1] = vr[1][j]; col[2] = vr[2][j]; col[3] = vr[3][j];
                *reinterpret_cast<short4v*>((char*)Vt + (vdc + j) * 128 + ((8 * vf) ^ (j << 4))) = col;
            }
        }
        __syncthreads();
        cur ^= 1;
    }

#pragma unroll
    for (int mi = 0; mi < 2; ++mi)
#pragma unroll
        for (int j = 0; j < 4; ++j) {
            float l = lrow[mi][j];
#pragma unroll
            for (int mm = 1; mm < 16; mm <<= 1) l += __shfl_xor(l, mm);
            const int r = t0 + w * 32 + mi * 16 + hi * 4 + j;
            float inv = 1.f / l;
            bf16* yr = y + ((size_t)(b * TT) + r) * CC + h * HDq;
#pragma unroll
            for (int n = 0; n < 8; ++n)
                yr[n * 16 + fr] = __float2bfloat16(acc[mi][n][j] * inv);
        }
}

extern "C" void kernel_launch(void* const* d_in, const int* in_sizes, int n_in,
                              void* d_out, int out_size, void* d_ws, size_t ws_size,
                              hipStream_t stream) {
    const float* x     = (const float*)d_in[0];
    const float* ve    = (const float*)d_in[1];
    const float* cosb  = (const float*)d_in[2];
    const float* sinb  = (const float*)d_in[3];
    const float* Wq    = (const float*)d_in[4];
    const float* Wk    = (const float*)d_in[5];
    const float* Wv    = (const float*)d_in[6];
    const float* Wproj = (const float*)d_in[7];
    const float* Wgate = (const float*)d_in[8];
    const int*   winp  = (const int*)d_in[9];

    bf16* xb     = (bf16*)d_ws;
    bf16* wqkvb  = xb + (size_t)ROWS * CC;
    bf16* wprojb = wqkvb + (size_t)NQKV * CC;
    bf16* qkvb   = wprojb + (size_t)CC * CC;
    float4* csT  = (float4*)(qkvb + (size_t)ROWS * NQKV);   // 1 MB packed cos/sin
    bf16* yb     = xb;   // alias: xb dead after qkv GEMM

    // 1) fused casts (Wq/Wk rows chunk-swapped for the RoPE-local epilogue)
    cast_all<<<18432, 256, 0, stream>>>(x, Wq, Wk, Wv, Wproj, xb);

    // 1b) packed cos/sin table
    prep_cs<<<256, 256, 0, stream>>>(cosb, sinb, csT);

    // 2) qkv = x @ [Wq;Wk;Wv]^T, ring-of-4 counted pipeline, fused postproc
    gemm_qkv<<<dim3(ROWS / 256, NQKV / 256), 512, 0, stream>>>(xb, wqkvb, qkvb,
                                                               x, ve, csT, Wgate);

    // 3) MFMA flash attention -> yb
    attn_mfma<<<BB * NHq * (TT / 128), 256, 0, stream>>>(qkvb, yb, winp);

    // 4) out = y @ Wproj^T (fp32 out)
    gemm_bt<1><<<dim3(ROWS / 128, CC / 128), 256, 0, stream>>>(yb, wprojb, d_out, ROWS, CC, CC);
}

// Round 11
// 248.651 us; speedup vs baseline: 1.0133x; 1.0133x over previous
//
#include <hip/hip_runtime.h>
#include <hip/hip_bf16.h>

// Problem constants (reference: B=2, T=2048, C=2048, NH=16, NKV=4, HD=128, GATE_CH=12)
#define BB   2
#define TT   2048
#define CC   2048
#define NHq  16
#define NKVq 4
#define HDq  128
#define ROWS (BB*TT)          // 4096
#define NQKV (NHq*HDq + 2*NKVq*HDq)  // 3072

using bf16 = __hip_bfloat16;
using short8  = __attribute__((ext_vector_type(8))) short;
using short4v = __attribute__((ext_vector_type(4))) short;
using f32x4   = __attribute__((ext_vector_type(4))) float;

#define MFMA16(a,b,c) __builtin_amdgcn_mfma_f32_16x16x32_bf16((a),(b),(c),0,0,0)

// async global->LDS, 16B per lane. LDS dest must be wave-uniform-base + lane*16.
__device__ __forceinline__ void gll16(const bf16* g, void* l) {
    __builtin_amdgcn_global_load_lds((const __attribute__((address_space(1))) void*)g,
                                     (__attribute__((address_space(3))) void*)l,
                                     16, 0, 0);
}

// ---------------- fused cast: all fp32 inputs -> contiguous bf16 ws regions ----------------
// dst layout: [xb 8388608 | wq 4194304 | wk 1048576 | wv 1048576 | wproj 4194304]
// Wq/Wk head-local rows are INTERLEAVE-permuted: orig 16-row frag f -> perm pos
// (f<4 ? 2f : 2(f-4)+1), so RoPE partners (d, d+64) sit in ADJACENT perm frags.
__global__ void cast_all(const float* __restrict__ x,  const float* __restrict__ wq,
                         const float* __restrict__ wk, const float* __restrict__ wv,
                         const float* __restrict__ wp, bf16* __restrict__ dst) {
    long e = ((long)blockIdx.x * 256 + threadIdx.x) * 4;
    const float* src; long off; long dsto = e; int permute = 0; long rbase = 0;
    if (e < 8388608L)       { src = x;  off = e; }
    else if (e < 12582912L) { src = wq; off = e - 8388608L;  permute = 1; rbase = 8388608L; }
    else if (e < 13631488L) { src = wk; off = e - 12582912L; permute = 1; rbase = 12582912L; }
    else if (e < 14680064L) { src = wv; off = e - 13631488L; }
    else                    { src = wp; off = e - 14680064L; }
    if (permute) {
        long row = off >> 11, col = off & 2047;
        int hl = (int)(row & 127);
        int f = hl >> 4, o = hl & 15;
        int f2 = (f < 4) ? (2 * f) : (2 * (f - 4) + 1);
        dsto = rbase + ((row & ~127L) | (f2 * 16 + o)) * 2048 + col;
    }
    float4 v = *reinterpret_cast<const float4*>(src + off);
    ushort4 o;
    o.x = __bfloat16_as_ushort(__float2bfloat16(v.x));
    o.y = __bfloat16_as_ushort(__float2bfloat16(v.y));
    o.z = __bfloat16_as_ushort(__float2bfloat16(v.z));
    o.w = __bfloat16_as_ushort(__float2bfloat16(v.w));
    *reinterpret_cast<ushort4*>(dst + dsto) = o;
}

// ---------------- prep: cos/sin float2 table, cs2[t*64+d] ----------------
__global__ void prep_cs2(const float* __restrict__ cosb, const float* __restrict__ sinb,
                         float2* __restrict__ cs) {
    int id = blockIdx.x * 256 + threadIdx.x;       // t*64 + d, 131072 total
    int t = id >> 6, d = id & 63;
    cs[id] = float2{cosb[t * 64 + d], sinb[t * 64 + d]};
}

// ---------------- bf16 MFMA GEMM (m97, natural block order), used for out-proj ----------------
template<int OUT_F32>
__global__ __launch_bounds__(256) void gemm_bt(const bf16* __restrict__ A,
                                               const bf16* __restrict__ B,
                                               void* __restrict__ Cp,
                                               int M, int N, int K) {
    const int bm = blockIdx.x * 128;
    const int bn = blockIdx.y * 128;
    const int tid = threadIdx.x;
    const int lane = tid & 63;
    const int w = tid >> 6;
    const int wr = w >> 1, wc = w & 1;   // 2x2 waves of 64x64

    __shared__ __align__(16) bf16 As[128 * 32];
    __shared__ __align__(16) bf16 Bs[128 * 32];

    f32x4 acc[4][4];
#pragma unroll
    for (int i = 0; i < 4; ++i)
#pragma unroll
        for (int j = 0; j < 4; ++j) acc[i][j] = f32x4{0.f, 0.f, 0.f, 0.f};

    const int srow = tid >> 2;
    const int scol = (tid & 3) * 8;

    for (int k0 = 0; k0 < K; k0 += 32) {
        __syncthreads();
#pragma unroll
        for (int p = 0; p < 2; ++p) {
            gll16(&A[(size_t)(bm + p * 64 + srow) * K + k0 + scol], (char*)As + p * 4096 + tid * 16);
            gll16(&B[(size_t)(bn + p * 64 + srow) * K + k0 + scol], (char*)Bs + p * 4096 + tid * 16);
        }
        __syncthreads();

        const int fr = lane & 15;
        const int kq = (lane >> 4) * 8;
        short8 af[4], bfr[4];
#pragma unroll
        for (int m = 0; m < 4; ++m)
            af[m] = *reinterpret_cast<const short8*>(&As[(wr * 64 + m * 16 + fr) * 32 + kq]);
#pragma unroll
        for (int n = 0; n < 4; ++n)
            bfr[n] = *reinterpret_cast<const short8*>(&Bs[(wc * 64 + n * 16 + fr) * 32 + kq]);
#pragma unroll
        for (int m = 0; m < 4; ++m)
#pragma unroll
            for (int n = 0; n < 4; ++n)
                acc[m][n] = MFMA16(af[m], bfr[n], acc[m][n]);
    }

    const int cr = (lane >> 4) * 4;
    const int cc = lane & 15;
#pragma unroll
    for (int m = 0; m < 4; ++m)
#pragma unroll
        for (int n = 0; n < 4; ++n) {
            int row = bm + wr * 64 + m * 16 + cr;
            int col = bn + wc * 64 + n * 16 + cc;
#pragma unroll
            for (int j = 0; j < 4; ++j) {
                float v = acc[m][n][j];
                if (OUT_F32) ((float*)Cp)[(size_t)(row + j) * N + col] = v;
                else         ((bf16*)Cp)[(size_t)(row + j) * N + col] = __float2bfloat16(v);
            }
        }
}

// ---------------- qkv GEMM v5: 256x256, BK=64, 8-wave, 8-PHASE schedule (m201 port) ----------------
// Wave rows: q*128 + wm*64 (q = m-quadrant); wave cols: p*128 + wn*32 (p = n-quadrant/head).
// Per phase: {ds_read quadrant frags || stage 1 half-tile (2 gll16)} -> barrier ->
// lgkmcnt(0) -> 16 MFMA (setprio) -> barrier. vmcnt(6) ONLY at phases 4 & 8.
// Stage X of tile T+2 exactly 1 phase after X's last read of T (same buffer, freed by barrier).
// chunk^(row&7) LDS swizzle both sides (R9: 0 conflicts). Fused RoPE/RMS/gate epilogue.
__global__ __launch_bounds__(512) void gemm_qkv(const bf16* __restrict__ A,
                                                const bf16* __restrict__ B,
                                                bf16* __restrict__ qkv,
                                                const float* __restrict__ x,
                                                const float* __restrict__ ve,
                                                const float2* __restrict__ cs2,
                                                const float* __restrict__ Wgate) {
    const int K = CC;                 // 2048; 32 K-tiles of 64; 16 iters of 2 tiles
    const int bm = blockIdx.x * 256;
    const int bn = blockIdx.y * 256;
    const int tid = threadIdx.x;      // 0..511
    const int lane = tid & 63;
    const int w = tid >> 6;           // 0..7
    const int wm = w >> 2;            // 0..1 (M)
    const int wn = w & 3;             // 0..3 (N)
    const int fr = lane & 15;
    const int hi = lane >> 4;

    __shared__ __align__(16) bf16 ldsA[2][16384];    // [buf][256 x 64], 64 KB
    __shared__ __align__(16) bf16 ldsB[2][16384];    // 64 KB
    __shared__ float exch[2][4][256];                // [head][wn][row] 8 KB
    __shared__ float gate_s[2][256];                 // 2 KB

    const bool isv = (bn >= 2560);
    if (isv) {
        const int r = tid & 255, kv = tid >> 8;
        const int kvh_w = ((bn - 2560) >> 7) + kv;
        float g = 0.f;
#pragma unroll
        for (int c = 0; c < 12; ++c) g += x[(size_t)(bm + r) * CC + c] * Wgate[kvh_w * 12 + c];
        gate_s[kv][r] = 3.0f / (1.0f + __expf(-g));
    }
    // drain gate loads so loop vmcnt counting starts from 0 outstanding
    asm volatile("s_waitcnt vmcnt(0)" ::: "memory");
    __builtin_amdgcn_sched_barrier(0);

    f32x4 acc[8][4];
#pragma unroll
    for (int i = 0; i < 8; ++i)
#pragma unroll
        for (int j = 0; j < 4; ++j) acc[i][j] = f32x4{0.f, 0.f, 0.f, 0.f};

    short8 areg[2][4];   // [kk][mf]
    short8 breg[2][2];   // [kk][nf]

    // ---- staging: half-tile h (128 rows) of tile into buf tile&1; 2 gll16/thread ----
#define STAGE_A(TILE, HALF) do {                                                     \
    const int _k0 = (TILE) * 64;                                                     \
    char* _dst = (char*)ldsA[(TILE) & 1] + (HALF) * 16384;                           \
    _Pragma("unroll")                                                                \
    for (int _i = 0; _i < 2; ++_i) {                                                 \
        int _row = (HALF) * 128 + _i * 64 + (tid >> 3);                              \
        int _sc = (tid & 7) ^ (_row & 7);                                            \
        gll16(&A[(size_t)(bm + _row) * K + _k0 + _sc * 8], _dst + _i * 8192 + tid * 16); \
    } } while (0)
#define STAGE_B(TILE, HALF) do {                                                     \
    const int _k0 = (TILE) * 64;                                                     \
    char* _dst = (char*)ldsB[(TILE) & 1] + (HALF) * 16384;                           \
    _Pragma("unroll")                                                                \
    for (int _i = 0; _i < 2; ++_i) {                                                 \
        int _row = (HALF) * 128 + _i * 64 + (tid >> 3);                              \
        int _sc = (tid & 7) ^ (_row & 7);                                            \
        gll16(&B[(size_t)(bn + _row) * K + _k0 + _sc * 8], _dst + _i * 8192 + tid * 16); \
    } } while (0)

    // ---- ds_reads (literal BUF/Q/P -> static reg indices) ----
#define DSA(BUF, Q) do {                                                             \
    _Pragma("unroll")                                                                \
    for (int _kk = 0; _kk < 2; ++_kk)                                                \
    _Pragma("unroll")                                                                \
    for (int _mf = 0; _mf < 4; ++_mf) {                                              \
        int _row = (Q) * 128 + wm * 64 + _mf * 16 + fr;                              \
        int _lch = (_kk * 4 + hi) ^ (_row & 7);                                      \
        areg[_kk][_mf] = *reinterpret_cast<const short8*>(                           \
            (const char*)ldsA[BUF] + _row * 128 + _lch * 16);                        \
    } } while (0)
#define DSB(BUF, P) do {                                                             \
    _Pragma("unroll")                                                                \
    for (int _kk = 0; _kk < 2; ++_kk)                                                \
    _Pragma("unroll")                                                                \
    for (int _nf = 0; _nf < 2; ++_nf) {                                              \
        int _row = (P) * 128 + wn * 32 + _nf * 16 + fr;                              \
        int _lch = (_kk * 4 + hi) ^ (_row & 7);                                      \
        breg[_kk][_nf] = *reinterpret_cast<const short8*>(                           \
            (const char*)ldsB[BUF] + _row * 128 + _lch * 16);                        \
    } } while (0)
#define MMA(Q, P) do {                                                               \
    __builtin_amdgcn_s_setprio(1);                                                   \
    _Pragma("unroll")                                                                \
    for (int _kk = 0; _kk < 2; ++_kk)                                                \
    _Pragma("unroll")                                                                \
    for (int _mf = 0; _mf < 4; ++_mf)                                                \
    _Pragma("unroll")                                                                \
    for (int _nf = 0; _nf < 2; ++_nf)                                                \
        acc[(Q) * 4 + _mf][(P) * 2 + _nf] =                                          \
            MFMA16(areg[_kk][_mf], breg[_kk][_nf], acc[(Q) * 4 + _mf][(P) * 2 + _nf]); \
    __builtin_amdgcn_s_setprio(0);                                                   \
    } while (0)
#define BARS do {                                                                    \
    __builtin_amdgcn_sched_barrier(0);                                               \
    __builtin_amdgcn_s_barrier();                                                    \
    asm volatile("s_waitcnt lgkmcnt(0)" ::: "memory");                               \
    __builtin_amdgcn_sched_barrier(0);                                               \
    } while (0)
#define BARE do {                                                                    \
    __builtin_amdgcn_sched_barrier(0);                                               \
    __builtin_amdgcn_s_barrier();                                                    \
    } while (0)

    // ---- prologue: T0 all 4 halves + T1.{A0,B1,A1}; land T0 ----
    STAGE_A(0, 0); STAGE_B(0, 0); STAGE_A(0, 1); STAGE_B(0, 1);
    STAGE_A(1, 0); STAGE_B(1, 1); STAGE_A(1, 1);
    asm volatile("s_waitcnt vmcnt(6)" ::: "memory");
    BARE;

    for (int it = 0; it < 16; ++it) {
        const int T = 2 * it;
        const bool st = (it < 15);
        // ph1: compute T(q0,p0); stage T+1.B0
        DSA(0, 0); DSB(0, 0);
        STAGE_B(T + 1, 0);
        BARS; MMA(0, 0); BARE;
        // ph2: (q0,p1); stage T+2.A0
        DSB(0, 1);
        if (st) STAGE_A(T + 2, 0);
        BARS; MMA(0, 1); BARE;
        // ph3: (q1,p1); stage T+2.B1
        DSA(0, 1);
        if (st) STAGE_B(T + 2, 1);
        BARS; MMA(1, 1); BARE;
        // ph4: (q1,p0); stage T+2.A1; counted vmcnt -> T+1 fully landed
        DSB(0, 0);
        if (st) STAGE_A(T + 2, 1);
        if (st) asm volatile("s_waitcnt vmcnt(6)" ::: "memory");
        else    asm volatile("s_waitcnt vmcnt(0)" ::: "memory");
        BARS; MMA(1, 0); BARE;
        // ph5: compute T+1(q0,p0); stage T+2.B0
        DSA(1, 0); DSB(1, 0);
        if (st) STAGE_B(T + 2, 0);
        BARS; MMA(0, 0); BARE;
        // ph6: (q0,p1); stage T+3.A0
        DSB(1, 1);
        if (st) STAGE_A(T + 3, 0);
        BARS; MMA(0, 1); BARE;
        // ph7: (q1,p1); stage T+3.B1
        DSA(1, 1);
        if (st) STAGE_B(T + 3, 1);
        BARS; MMA(1, 1); BARE;
        // ph8: (q1,p0); stage T+3.A1; counted vmcnt -> T+2 fully landed
        DSB(1, 0);
        if (st) STAGE_A(T + 3, 1);
        if (st) asm volatile("s_waitcnt vmcnt(6)" ::: "memory");
        else    asm volatile("s_waitcnt vmcnt(0)" ::: "memory");
        BARS; MMA(1, 0); BARE;
    }
    __syncthreads();

    // ---- fused epilogue ----
    // acc[mi][ni]: row = bm + (mi>>2)*128 + wm*64 + (mi&3)*16 + hi*4 + j
    //              col = bn + (ni>>1)*128 + wn*32 + (ni&1)*16 + fr
    const int hi4 = hi * 4;
    if (!isv) {
        // RoPE (perm frags 2wn/2wn+1 = orig d0/d0+64, d0 = wn*16+fr) + RMSNorm + *1.2
        const int d0 = wn * 16 + fr;
#pragma unroll
        for (int mi = 0; mi < 8; ++mi)
#pragma unroll
            for (int j = 0; j < 4; ++j) {
                const int lr = (mi >> 2) * 128 + wm * 64 + (mi & 3) * 16 + hi4 + j;
                const int t_ = (bm + lr) & (TT - 1);
                const float2 cs = cs2[(size_t)t_ * 64 + d0];
#pragma unroll
                for (int p = 0; p < 2; ++p) {
                    float x1 = acc[mi][2 * p][j], x2 = acc[mi][2 * p + 1][j];
                    float r1 =  x1 * cs.x + x2 * cs.y;
                    float r2 = -x1 * cs.y + x2 * cs.x;
                    acc[mi][2 * p][j] = r1; acc[mi][2 * p + 1][j] = r2;
                    float ss = r1 * r1 + r2 * r2;
#pragma unroll
                    for (int mm = 1; mm < 16; mm <<= 1) ss += __shfl_xor(ss, mm);
                    if (fr == 0) exch[p][wn][lr] = ss;
                }
            }
        __syncthreads();
#pragma unroll
        for (int mi = 0; mi < 8; ++mi)
#pragma unroll
            for (int j = 0; j < 4; ++j) {
                const int lr = (mi >> 2) * 128 + wm * 64 + (mi & 3) * 16 + hi4 + j;
                const int row = bm + lr;
#pragma unroll
                for (int p = 0; p < 2; ++p) {
                    float sst = exch[p][0][lr] + exch[p][1][lr] + exch[p][2][lr] + exch[p][3][lr];
                    float sc = rsqrtf(sst * (1.0f / 128.0f) + 1e-6f) * 1.2f;
                    bf16* o = qkv + (size_t)row * NQKV + bn + p * 128;
                    o[d0]      = __float2bfloat16(acc[mi][2 * p][j] * sc);
                    o[d0 + 64] = __float2bfloat16(acc[mi][2 * p + 1][j] * sc);
                }
            }
    } else {
        // v: gate + ve add
        const int kvb = (bn - 2560) >> 7;
#pragma unroll
        for (int mi = 0; mi < 8; ++mi)
#pragma unroll
            for (int j = 0; j < 4; ++j) {
                const int lr = (mi >> 2) * 128 + wm * 64 + (mi & 3) * 16 + hi4 + j;
                const int row = bm + lr;
#pragma unroll
                for (int p = 0; p < 2; ++p) {
                    const float g = gate_s[p][lr];
                    const float* vep = ve + (size_t)row * 512 + (kvb + p) * 128;
                    bf16* o = qkv + (size_t)row * NQKV + bn + p * 128;
#pragma unroll
                    for (int nf = 0; nf < 2; ++nf) {
                        int d = wn * 32 + nf * 16 + fr;
                        o[d] = __float2bfloat16(acc[mi][2 * p + nf][j] + g * vep[d]);
                    }
                }
            }
    }
#undef STAGE_A
#undef STAGE_B
#undef DSA
#undef DSB
#undef MMA
#undef BARS
#undef BARE
}

// ---------------- MFMA flash attention v5 (unchanged) ----------------
__global__ __launch_bounds__(256, 2) void attn_mfma(const bf16* __restrict__ qkv,
                                                    bf16* __restrict__ y,
                                                    const int* __restrict__ winp) {
    const int bid = blockIdx.x;
    const int group = bid >> 8, idx = bid & 255;
    const int bh = idx >> 3, jj = idx & 7;
    const int qt = group ? jj : (15 - jj);
    const int h = bh & 15, b = bh >> 4;
    const int t0 = qt * 128;
    const int kvh = h >> 2;
    const int tid = threadIdx.x;
    const int lane = tid & 63;
    const int w = tid >> 6;
    const int window = winp[0];

    __shared__ __align__(16) bf16 Ks[2][64 * 128];
    __shared__ __align__(16) bf16 Vt[128 * 64];
    __shared__ __align__(16) bf16 Ps[4][32 * 64];

    const int fr = lane & 15;
    const int kq = (lane >> 4) * 8;
    const int hi = lane >> 4;

    short8 qf[2][4];
#pragma unroll
    for (int mi = 0; mi < 2; ++mi) {
        const bf16* qp = qkv + ((size_t)(b * TT) + t0 + w * 32 + mi * 16 + fr) * NQKV + h * HDq;
#pragma unroll
        for (int c = 0; c < 4; ++c)
            qf[mi][c] = *reinterpret_cast<const short8*>(&qp[c * 32 + kq]);
    }

    f32x4 acc[2][8];
#pragma unroll
    for (int mi = 0; mi < 2; ++mi)
#pragma unroll
        for (int n = 0; n < 8; ++n) acc[mi][n] = f32x4{0.f, 0.f, 0.f, 0.f};
    float m2[2][4], lrow[2][4];
#pragma unroll
    for (int mi = 0; mi < 2; ++mi)
#pragma unroll
        for (int j = 0; j < 4; ++j) { m2[mi][j] = -1e30f; lrow[mi][j] = 0.f; }

    int s_lo = t0 - window; if (s_lo < 0) s_lo = 0; s_lo &= ~63;
    const int s_end = t0 + 128;

    const bf16* Kg = qkv + (size_t)b * TT * NQKV + 2048 + kvh * HDq;
    const bf16* Vg = Kg + 512;

    const int str = tid >> 4;
    const int sti = tid & 15;
    const int vf  = tid & 15;
    const int vdc = (tid >> 4) * 8;
    const float scl2 = 0.08838834764831845f * 1.4426950408889634f;
    const float THR2 = 11.54f;

    short8 vr[4];

#pragma unroll
    for (int p = 0; p < 4; ++p) {
        int row = p * 16 + str;
        int c16 = sti ^ (row & 7);
        gll16(&Kg[(size_t)(s_lo + row) * NQKV + c16 * 8], (char*)Ks + p * 4096 + tid * 16);
    }
#pragma unroll
    for (int i = 0; i < 4; ++i)
        vr[i] = *reinterpret_cast<const short8*>(&Vg[(size_t)(s_lo + 16 * i + vf) * NQKV + vdc]);
#pragma unroll
    for (int j = 0; j < 8; ++j) {
        short4v col;
        col[0] = vr[0][j]; col[1] = vr[1][j]; col[2] = vr[2][j]; col[3] = vr[3][j];
        *reinterpret_cast<short4v*>((char*)Vt + (vdc + j) * 128 + ((8 * vf) ^ (j << 4))) = col;
    }
    __syncthreads();

    int cur = 0;
    for (int sk = s_lo; sk < s_end; sk += 64) {
        const bool hn = (sk + 64 < s_end);
        if (hn) {
#pragma unroll
            for (int p = 0; p < 4; ++p) {
                int row = p * 16 + str;
                int c16 = sti ^ (row & 7);
                gll16(&Kg[(size_t)(sk + 64 + row) * NQKV + c16 * 8],
                      (char*)Ks + (cur ^ 1) * 16384 + p * 4096 + tid * 16);
            }
#pragma unroll
            for (int i = 0; i < 4; ++i)
                vr[i] = *reinterpret_cast<const short8*>(&Vg[(size_t)(sk + 64 + 16 * i + vf) * NQKV + vdc]);
        }

        f32x4 S[2][4];
#pragma unroll
        for (int mi = 0; mi < 2; ++mi)
#pragma unroll
            for (int n = 0; n < 4; ++n) S[mi][n] = f32x4{0.f, 0.f, 0.f, 0.f};
        __builtin_amdgcn_s_setprio(1);
#pragma unroll
        for (int n = 0; n < 4; ++n) {
            int rb = n * 16 + fr;
#pragma unroll
            for (int c = 0; c < 4; ++c) {
                int colb = c * 64 + kq * 2;
                short8 kf = *reinterpret_cast<const short8*>(
                    (const char*)Ks + cur * 16384 + rb * 256 + (colb ^ ((rb & 7) << 4)));
                S[0][n] = MFMA16(qf[0][c], kf, S[0][n]);
                S[1][n] = MFMA16(qf[1][c], kf, S[1][n]);
            }
        }
        __builtin_amdgcn_s_setprio(0);

        const int rw0 = t0 + w * 32;
        const bool interior = (sk + 63 <= rw0) && (rw0 + 31 - sk <= window);
#pragma unroll
        for (int mi = 0; mi < 2; ++mi) {
#pragma unroll
            for (int j = 0; j < 4; ++j) {
                const int rl = hi * 4 + j;
                float s0, s1, s2, s3;
                if (interior) {
                    s0 = S[mi][0][j] * scl2; s1 = S[mi][1][j] * scl2;
                    s2 = S[mi][2][j] * scl2; s3 = S[mi][3][j] * scl2;
                } else {
                    const int r = rw0 + mi * 16 + rl;
                    int c0 = sk + fr, c1 = c0 + 16, c2 = c0 + 32, c3 = c0 + 48;
                    s0 = (c0 <= r && r - c0 <= window) ? S[mi][0][j] * scl2 : -1e30f;
                    s1 = (c1 <= r && r - c1 <= window) ? S[mi][1][j] * scl2 : -1e30f;
                    s2 = (c2 <= r && r - c2 <= window) ? S[mi][2][j] * scl2 : -1e30f;
                    s3 = (c3 <= r && r - c3 <= window) ? S[mi][3][j] * scl2 : -1e30f;
                }
                float pm = fmaxf(fmaxf(s0, s1), fmaxf(s2, s3));
                if (!__all(pm <= m2[mi][j] + THR2)) {
                    float pr = pm;
#pragma unroll
                    for (int mm = 1; mm < 16; mm <<= 1) pr = fmaxf(pr, __shfl_xor(pr, mm));
                    float nm = fmaxf(m2[mi][j], pr);
                    float corr = exp2f(m2[mi][j] - nm);
                    m2[mi][j] = nm;
                    lrow[mi][j] *= corr;
#pragma unroll
                    for (int n = 0; n < 8; ++n) acc[mi][n][j] *= corr;
                }
                float p0 = exp2f(s0 - m2[mi][j]);
                float p1 = exp2f(s1 - m2[mi][j]);
                float p2 = exp2f(s2 - m2[mi][j]);
                float p3 = exp2f(s3 - m2[mi][j]);
                if (!interior) {
                    p0 = (s0 > -1e29f) ? p0 : 0.f;
                    p1 = (s1 > -1e29f) ? p1 : 0.f;
                    p2 = (s2 > -1e29f) ? p2 : 0.f;
                    p3 = (s3 > -1e29f) ? p3 : 0.f;
                }
                lrow[mi][j] += (p0 + p1) + (p2 + p3);
                short4v pk;
                pk[0] = (short)__bfloat16_as_ushort(__float2bfloat16(p0));
                pk[1] = (short)__bfloat16_as_ushort(__float2bfloat16(p1));
                pk[2] = (short)__bfloat16_as_ushort(__float2bfloat16(p2));
                pk[3] = (short)__bfloat16_as_ushort(__float2bfloat16(p3));
                const int prow = mi * 16 + rl;
                *reinterpret_cast<short4v*>(
                    (char*)Ps + w * 4096 + prow * 128 + ((8 * fr) ^ ((prow & 7) << 4))) = pk;
            }
        }

        __builtin_amdgcn_s_setprio(1);
#pragma unroll
        for (int c2 = 0; c2 < 2; ++c2) {
            short8 pa0 = *reinterpret_cast<const short8*>(
                (char*)Ps + w * 4096 + fr * 128 + ((c2 * 64 + hi * 16) ^ ((fr & 7) << 4)));
            short8 pa1 = *reinterpret_cast<const short8*>(
                (char*)Ps + w * 4096 + (16 + fr) * 128 + ((c2 * 64 + hi * 16) ^ ((fr & 7) << 4)));
#pragma unroll
            for (int n = 0; n < 8; ++n) {
                short8 vb = *reinterpret_cast<const short8*>(
                    (char*)Vt + (n * 16 + fr) * 128 + ((c2 * 64 + hi * 16) ^ ((fr & 7) << 4)));
                acc[0][n] = MFMA16(pa0, vb, acc[0][n]);
                acc[1][n] = MFMA16(pa1, vb, acc[1][n]);
            }
        }
        __builtin_amdgcn_s_setprio(0);

        __syncthreads();
        if (hn) {
#pragma unroll
            for (int j = 0; j < 8; ++j) {
                short4v col;
                col[0] = vr[0][j]; col[1] = vr[1][j]; col[2] = vr[2][j]; col[3] = vr[3][j];
                *reinterpret_cast<short4v*>((char*)Vt + (vdc + j) * 128 + ((8 * vf) ^ (j << 4))) = col;
            }
        }
        __syncthreads();
        cur ^= 1;
    }

#pragma unroll
    for (int mi = 0; mi < 2; ++mi)
#pragma unroll
        for (int j = 0; j < 4; ++j) {
            float l = lrow[mi][j];
#pragma unroll
            for (int mm = 1; mm < 16; mm <<= 1) l += __shfl_xor(l, mm);
            const int r = t0 + w * 32 + mi * 16 + hi * 4 + j;
            float inv = 1.f / l;
            bf16* yr = y + ((size_t)(b * TT) + r) * CC + h * HDq;
#pragma unroll
            for (int n = 0; n < 8; ++n)
                yr[n * 16 + fr] = __float2bfloat16(acc[mi][n][j] * inv);
        }
}

extern "C" void kernel_launch(void* const* d_in, const int* in_sizes, int n_in,
                              void* d_out, int out_size, void* d_ws, size_t ws_size,
                              hipStream_t stream) {
    const float* x     = (const float*)d_in[0];
    const float* ve    = (const float*)d_in[1];
    const float* cosb  = (const float*)d_in[2];
    const float* sinb  = (const float*)d_in[3];
    const float* Wq    = (const float*)d_in[4];
    const float* Wk    = (const float*)d_in[5];
    const float* Wv    = (const float*)d_in[6];
    const float* Wproj = (const float*)d_in[7];
    const float* Wgate = (const float*)d_in[8];
    const int*   winp  = (const int*)d_in[9];

    bf16* xb     = (bf16*)d_ws;
    bf16* wqkvb  = xb + (size_t)ROWS * CC;
    bf16* wprojb = wqkvb + (size_t)NQKV * CC;
    bf16* qkvb   = wprojb + (size_t)CC * CC;
    float2* csT  = (float2*)(qkvb + (size_t)ROWS * NQKV);   // 1 MB cos/sin float2
    bf16* yb     = xb;   // alias: xb dead after qkv GEMM

    // 1) fused casts (Wq/Wk rows interleave-permuted for the RoPE-local epilogue)
    cast_all<<<18432, 256, 0, stream>>>(x, Wq, Wk, Wv, Wproj, xb);

    // 1b) cos/sin table
    prep_cs2<<<512, 256, 0, stream>>>(cosb, sinb, csT);

    // 2) qkv = x @ [Wq;Wk;Wv]^T, 8-phase 256^2 pipeline, fused postproc
    gemm_qkv<<<dim3(ROWS / 256, NQKV / 256), 512, 0, stream>>>(xb, wqkvb, qkvb,
                                                               x, ve, csT, Wgate);

    // 3) MFMA flash attention -> yb
    attn_mfma<<<BB * NHq * (TT / 128), 256, 0, stream>>>(qkvb, yb, winp);

    // 4) out = y @ Wproj^T (fp32 out)
    gemm_bt<1><<<dim3(ROWS / 128, CC / 128), 256, 0, stream>>>(yb, wprojb, d_out, ROWS, CC, CC);
}

// Round 12
// 218.540 us; speedup vs baseline: 1.1529x; 1.1378x over previous
//
#include <hip/hip_runtime.h>
#include <hip/hip_bf16.h>

// Problem constants (reference: B=2, T=2048, C=2048, NH=16, NKV=4, HD=128, GATE_CH=12)
#define BB   2
#define TT   2048
#define CC   2048
#define NHq  16
#define NKVq 4
#define HDq  128
#define ROWS (BB*TT)          // 4096
#define NQKV (NHq*HDq + 2*NKVq*HDq)  // 3072

using bf16 = __hip_bfloat16;
using short8  = __attribute__((ext_vector_type(8))) short;
using short4v = __attribute__((ext_vector_type(4))) short;
using f32x4   = __attribute__((ext_vector_type(4))) float;

#define MFMA16(a,b,c) __builtin_amdgcn_mfma_f32_16x16x32_bf16((a),(b),(c),0,0,0)

// async global->LDS, 16B per lane. LDS dest must be wave-uniform-base + lane*16.
__device__ __forceinline__ void gll16(const bf16* g, void* l) {
    __builtin_amdgcn_global_load_lds((const __attribute__((address_space(1))) void*)g,
                                     (__attribute__((address_space(3))) void*)l,
                                     16, 0, 0);
}

// ---------------- fused cast: all fp32 inputs -> contiguous bf16 ws regions ----------------
// dst layout: [xb 8388608 | wq 4194304 | wk 1048576 | wv 1048576 | wproj 4194304]
__global__ void cast_all(const float* __restrict__ x,  const float* __restrict__ wq,
                         const float* __restrict__ wk, const float* __restrict__ wv,
                         const float* __restrict__ wp, bf16* __restrict__ dst) {
    long e = ((long)blockIdx.x * 256 + threadIdx.x) * 4;
    const float* src; long off;
    if (e < 8388608L)       { src = x;  off = e; }
    else if (e < 12582912L) { src = wq; off = e - 8388608L; }
    else if (e < 13631488L) { src = wk; off = e - 12582912L; }
    else if (e < 14680064L) { src = wv; off = e - 13631488L; }
    else                    { src = wp; off = e - 14680064L; }
    float4 v = *reinterpret_cast<const float4*>(src + off);
    ushort4 o;
    o.x = __bfloat16_as_ushort(__float2bfloat16(v.x));
    o.y = __bfloat16_as_ushort(__float2bfloat16(v.y));
    o.z = __bfloat16_as_ushort(__float2bfloat16(v.z));
    o.w = __bfloat16_as_ushort(__float2bfloat16(v.w));
    *reinterpret_cast<ushort4*>(dst + e) = o;
}

// ---------------- bf16 MFMA GEMM (m97, natural block order) ----------------
// C[M,N] = A[M,K] * B[N,K]^T. 128x128 tile, BK=32, linear LDS, global_load_lds w=16.
template<int OUT_F32>
__global__ __launch_bounds__(256) void gemm_bt(const bf16* __restrict__ A,
                                               const bf16* __restrict__ B,
                                               void* __restrict__ Cp,
                                               int M, int N, int K) {
    const int bm = blockIdx.x * 128;
    const int bn = blockIdx.y * 128;
    const int tid = threadIdx.x;
    const int lane = tid & 63;
    const int w = tid >> 6;
    const int wr = w >> 1, wc = w & 1;   // 2x2 waves of 64x64

    __shared__ __align__(16) bf16 As[128 * 32];
    __shared__ __align__(16) bf16 Bs[128 * 32];

    f32x4 acc[4][4];
#pragma unroll
    for (int i = 0; i < 4; ++i)
#pragma unroll
        for (int j = 0; j < 4; ++j) acc[i][j] = f32x4{0.f, 0.f, 0.f, 0.f};

    const int srow = tid >> 2;
    const int scol = (tid & 3) * 8;

    for (int k0 = 0; k0 < K; k0 += 32) {
        __syncthreads();
#pragma unroll
        for (int p = 0; p < 2; ++p) {
            gll16(&A[(size_t)(bm + p * 64 + srow) * K + k0 + scol], (char*)As + p * 4096 + tid * 16);
            gll16(&B[(size_t)(bn + p * 64 + srow) * K + k0 + scol], (char*)Bs + p * 4096 + tid * 16);
        }
        __syncthreads();

        const int fr = lane & 15;
        const int kq = (lane >> 4) * 8;
        short8 af[4], bfr[4];
#pragma unroll
        for (int m = 0; m < 4; ++m)
            af[m] = *reinterpret_cast<const short8*>(&As[(wr * 64 + m * 16 + fr) * 32 + kq]);
#pragma unroll
        for (int n = 0; n < 4; ++n)
            bfr[n] = *reinterpret_cast<const short8*>(&Bs[(wc * 64 + n * 16 + fr) * 32 + kq]);
#pragma unroll
        for (int m = 0; m < 4; ++m)
#pragma unroll
            for (int n = 0; n < 4; ++n)
                acc[m][n] = MFMA16(af[m], bfr[n], acc[m][n]);
    }

    const int cr = (lane >> 4) * 4;
    const int cc = lane & 15;
#pragma unroll
    for (int m = 0; m < 4; ++m)
#pragma unroll
        for (int n = 0; n < 4; ++n) {
            int row = bm + wr * 64 + m * 16 + cr;
            int col = bn + wc * 64 + n * 16 + cc;
#pragma unroll
            for (int j = 0; j < 4; ++j) {
                float v = acc[m][n][j];
                if (OUT_F32) ((float*)Cp)[(size_t)(row + j) * N + col] = v;
                else         ((bf16*)Cp)[(size_t)(row + j) * N + col] = __float2bfloat16(v);
            }
        }
}

// ---------------- postproc: gate+ve add on V, RoPE+RMSNorm on Q,K (in place) ----------------
// one block per (b,t) row; qkv row layout: [q 0..2047 | k 2048..2559 | v 2560..3071]
__global__ __launch_bounds__(256) void postproc(const float* __restrict__ x,
                                                const float* __restrict__ ve,
                                                const float* __restrict__ cosb,
                                                const float* __restrict__ sinb,
                                                const float* __restrict__ Wgate,
                                                bf16* __restrict__ qkv) {
    const int row = blockIdx.x;            // b*T + t
    const int t = row & (TT - 1);
    const int tid = threadIdx.x;
    __shared__ float gate_s[NKVq];
    if (tid < NKVq) {
        float g = 0.f;
#pragma unroll
        for (int c = 0; c < 12; ++c) g += x[(size_t)row * CC + c] * Wgate[tid * 12 + c];
        gate_s[tid] = 3.0f / (1.0f + __expf(-g));
    }
    __syncthreads();

    bf16* qkvr = qkv + (size_t)row * NQKV;

#pragma unroll
    for (int i = 0; i < 2; ++i) {
        int idx = tid + i * 256;
        float v = __bfloat162float(qkvr[2560 + idx]);
        v += gate_s[idx >> 7] * ve[(size_t)row * 512 + idx];
        qkvr[2560 + idx] = __float2bfloat16(v);
    }

    const int lane = tid & 63;
    const int w = tid >> 6;
    const float cv = cosb[(size_t)t * 64 + lane];
    const float sv = sinb[(size_t)t * 64 + lane];
    for (int hh = w; hh < NHq + NKVq; hh += 4) {
        int off = (hh < NHq) ? hh * HDq : 2048 + (hh - NHq) * HDq;
        float x1 = __bfloat162float(qkvr[off + lane]);
        float x2 = __bfloat162float(qkvr[off + 64 + lane]);
        float r1 =  x1 * cv + x2 * sv;
        float r2 = -x1 * sv + x2 * cv;
        float ss = r1 * r1 + r2 * r2;
#pragma unroll
        for (int m = 1; m < 64; m <<= 1) ss += __shfl_xor(ss, m);
        float sc = rsqrtf(ss * (1.0f / 128.0f) + 1e-6f) * 1.2f;
        qkvr[off + lane]      = __float2bfloat16(r1 * sc);
        qkvr[off + 64 + lane] = __float2bfloat16(r2 * sc);
    }
}

// ---------------- MFMA flash attention v5 (frozen: 66 us config) ----------------
__global__ __launch_bounds__(256, 2) void attn_mfma(const bf16* __restrict__ qkv,
                                                    bf16* __restrict__ y,
                                                    const int* __restrict__ winp) {
    const int bid = blockIdx.x;
    const int group = bid >> 8, idx = bid & 255;
    const int bh = idx >> 3, jj = idx & 7;
    const int qt = group ? jj : (15 - jj);
    const int h = bh & 15, b = bh >> 4;
    const int t0 = qt * 128;
    const int kvh = h >> 2;
    const int tid = threadIdx.x;
    const int lane = tid & 63;
    const int w = tid >> 6;
    const int window = winp[0];

    __shared__ __align__(16) bf16 Ks[2][64 * 128];
    __shared__ __align__(16) bf16 Vt[128 * 64];
    __shared__ __align__(16) bf16 Ps[4][32 * 64];

    const int fr = lane & 15;
    const int kq = (lane >> 4) * 8;
    const int hi = lane >> 4;

    short8 qf[2][4];
#pragma unroll
    for (int mi = 0; mi < 2; ++mi) {
        const bf16* qp = qkv + ((size_t)(b * TT) + t0 + w * 32 + mi * 16 + fr) * NQKV + h * HDq;
#pragma unroll
        for (int c = 0; c < 4; ++c)
            qf[mi][c] = *reinterpret_cast<const short8*>(&qp[c * 32 + kq]);
    }

    f32x4 acc[2][8];
#pragma unroll
    for (int mi = 0; mi < 2; ++mi)
#pragma unroll
        for (int n = 0; n < 8; ++n) acc[mi][n] = f32x4{0.f, 0.f, 0.f, 0.f};
    float m2[2][4], lrow[2][4];
#pragma unroll
    for (int mi = 0; mi < 2; ++mi)
#pragma unroll
        for (int j = 0; j < 4; ++j) { m2[mi][j] = -1e30f; lrow[mi][j] = 0.f; }

    int s_lo = t0 - window; if (s_lo < 0) s_lo = 0; s_lo &= ~63;
    const int s_end = t0 + 128;

    const bf16* Kg = qkv + (size_t)b * TT * NQKV + 2048 + kvh * HDq;
    const bf16* Vg = Kg + 512;

    const int str = tid >> 4;
    const int sti = tid & 15;
    const int vf  = tid & 15;
    const int vdc = (tid >> 4) * 8;
    const float scl2 = 0.08838834764831845f * 1.4426950408889634f;
    const float THR2 = 11.54f;

    short8 vr[4];

#pragma unroll
    for (int p = 0; p < 4; ++p) {
        int row = p * 16 + str;
        int c16 = sti ^ (row & 7);
        gll16(&Kg[(size_t)(s_lo + row) * NQKV + c16 * 8], (char*)Ks + p * 4096 + tid * 16);
    }
#pragma unroll
    for (int i = 0; i < 4; ++i)
        vr[i] = *reinterpret_cast<const short8*>(&Vg[(size_t)(s_lo + 16 * i + vf) * NQKV + vdc]);
#pragma unroll
    for (int j = 0; j < 8; ++j) {
        short4v col;
        col[0] = vr[0][j]; col[1] = vr[1][j]; col[2] = vr[2][j]; col[3] = vr[3][j];
        *reinterpret_cast<short4v*>((char*)Vt + (vdc + j) * 128 + ((8 * vf) ^ (j << 4))) = col;
    }
    __syncthreads();

    int cur = 0;
    for (int sk = s_lo; sk < s_end; sk += 64) {
        const bool hn = (sk + 64 < s_end);
        if (hn) {
#pragma unroll
            for (int p = 0; p < 4; ++p) {
                int row = p * 16 + str;
                int c16 = sti ^ (row & 7);
                gll16(&Kg[(size_t)(sk + 64 + row) * NQKV + c16 * 8],
                      (char*)Ks + (cur ^ 1) * 16384 + p * 4096 + tid * 16);
            }
#pragma unroll
            for (int i = 0; i < 4; ++i)
                vr[i] = *reinterpret_cast<const short8*>(&Vg[(size_t)(sk + 64 + 16 * i + vf) * NQKV + vdc]);
        }

        f32x4 S[2][4];
#pragma unroll
        for (int mi = 0; mi < 2; ++mi)
#pragma unroll
            for (int n = 0; n < 4; ++n) S[mi][n] = f32x4{0.f, 0.f, 0.f, 0.f};
        __builtin_amdgcn_s_setprio(1);
#pragma unroll
        for (int n = 0; n < 4; ++n) {
            int rb = n * 16 + fr;
#pragma unroll
            for (int c = 0; c < 4; ++c) {
                int colb = c * 64 + kq * 2;
                short8 kf = *reinterpret_cast<const short8*>(
                    (const char*)Ks + cur * 16384 + rb * 256 + (colb ^ ((rb & 7) << 4)));
                S[0][n] = MFMA16(qf[0][c], kf, S[0][n]);
                S[1][n] = MFMA16(qf[1][c], kf, S[1][n]);
            }
        }
        __builtin_amdgcn_s_setprio(0);

        const int rw0 = t0 + w * 32;
        const bool interior = (sk + 63 <= rw0) && (rw0 + 31 - sk <= window);
#pragma unroll
        for (int mi = 0; mi < 2; ++mi) {
#pragma unroll
            for (int j = 0; j < 4; ++j) {
                const int rl = hi * 4 + j;
                float s0, s1, s2, s3;
                if (interior) {
                    s0 = S[mi][0][j] * scl2; s1 = S[mi][1][j] * scl2;
                    s2 = S[mi][2][j] * scl2; s3 = S[mi][3][j] * scl2;
                } else {
                    const int r = rw0 + mi * 16 + rl;
                    int c0 = sk + fr, c1 = c0 + 16, c2 = c0 + 32, c3 = c0 + 48;
                    s0 = (c0 <= r && r - c0 <= window) ? S[mi][0][j] * scl2 : -1e30f;
                    s1 = (c1 <= r && r - c1 <= window) ? S[mi][1][j] * scl2 : -1e30f;
                    s2 = (c2 <= r && r - c2 <= window) ? S[mi][2][j] * scl2 : -1e30f;
                    s3 = (c3 <= r && r - c3 <= window) ? S[mi][3][j] * scl2 : -1e30f;
                }
                float pm = fmaxf(fmaxf(s0, s1), fmaxf(s2, s3));
                if (!__all(pm <= m2[mi][j] + THR2)) {
                    float pr = pm;
#pragma unroll
                    for (int mm = 1; mm < 16; mm <<= 1) pr = fmaxf(pr, __shfl_xor(pr, mm));
                    float nm = fmaxf(m2[mi][j], pr);
                    float corr = exp2f(m2[mi][j] - nm);
                    m2[mi][j] = nm;
                    lrow[mi][j] *= corr;
#pragma unroll
                    for (int n = 0; n < 8; ++n) acc[mi][n][j] *= corr;
                }
                float p0 = exp2f(s0 - m2[mi][j]);
                float p1 = exp2f(s1 - m2[mi][j]);
                float p2 = exp2f(s2 - m2[mi][j]);
                float p3 = exp2f(s3 - m2[mi][j]);
                if (!interior) {
                    p0 = (s0 > -1e29f) ? p0 : 0.f;
                    p1 = (s1 > -1e29f) ? p1 : 0.f;
                    p2 = (s2 > -1e29f) ? p2 : 0.f;
                    p3 = (s3 > -1e29f) ? p3 : 0.f;
                }
                lrow[mi][j] += (p0 + p1) + (p2 + p3);
                short4v pk;
                pk[0] = (short)__bfloat16_as_ushort(__float2bfloat16(p0));
                pk[1] = (short)__bfloat16_as_ushort(__float2bfloat16(p1));
                pk[2] = (short)__bfloat16_as_ushort(__float2bfloat16(p2));
                pk[3] = (short)__bfloat16_as_ushort(__float2bfloat16(p3));
                const int prow = mi * 16 + rl;
                *reinterpret_cast<short4v*>(
                    (char*)Ps + w * 4096 + prow * 128 + ((8 * fr) ^ ((prow & 7) << 4))) = pk;
            }
        }

        __builtin_amdgcn_s_setprio(1);
#pragma unroll
        for (int c2 = 0; c2 < 2; ++c2) {
            short8 pa0 = *reinterpret_cast<const short8*>(
                (char*)Ps + w * 4096 + fr * 128 + ((c2 * 64 + hi * 16) ^ ((fr & 7) << 4)));
            short8 pa1 = *reinterpret_cast<const short8*>(
                (char*)Ps + w * 4096 + (16 + fr) * 128 + ((c2 * 64 + hi * 16) ^ ((fr & 7) << 4)));
#pragma unroll
            for (int n = 0; n < 8; ++n) {
                short8 vb = *reinterpret_cast<const short8*>(
                    (char*)Vt + (n * 16 + fr) * 128 + ((c2 * 64 + hi * 16) ^ ((fr & 7) << 4)));
                acc[0][n] = MFMA16(pa0, vb, acc[0][n]);
                acc[1][n] = MFMA16(pa1, vb, acc[1][n]);
            }
        }
        __builtin_amdgcn_s_setprio(0);

        __syncthreads();
        if (hn) {
#pragma unroll
            for (int j = 0; j < 8; ++j) {
                short4v col;
                col[0] = vr[0][j]; col[1] = vr[1][j]; col[2] = vr[2][j]; col[3] = vr[3][j];
                *reinterpret_cast<short4v*>((char*)Vt + (vdc + j) * 128 + ((8 * vf) ^ (j << 4))) = col;
            }
        }
        __syncthreads();
        cur ^= 1;
    }

#pragma unroll
    for (int mi = 0; mi < 2; ++mi)
#pragma unroll
        for (int j = 0; j < 4; ++j) {
            float l = lrow[mi][j];
#pragma unroll
            for (int mm = 1; mm < 16; mm <<= 1) l += __shfl_xor(l, mm);
            const int r = t0 + w * 32 + mi * 16 + hi * 4 + j;
            float inv = 1.f / l;
            bf16* yr = y + ((size_t)(b * TT) + r) * CC + h * HDq;
#pragma unroll
            for (int n = 0; n < 8; ++n)
                yr[n * 16 + fr] = __float2bfloat16(acc[mi][n][j] * inv);
        }
}

extern "C" void kernel_launch(void* const* d_in, const int* in_sizes, int n_in,
                              void* d_out, int out_size, void* d_ws, size_t ws_size,
                              hipStream_t stream) {
    const float* x     = (const float*)d_in[0];
    const float* ve    = (const float*)d_in[1];
    const float* cosb  = (const float*)d_in[2];
    const float* sinb  = (const float*)d_in[3];
    const float* Wq    = (const float*)d_in[4];
    const float* Wk    = (const float*)d_in[5];
    const float* Wv    = (const float*)d_in[6];
    const float* Wproj = (const float*)d_in[7];
    const float* Wgate = (const float*)d_in[8];
    const int*   winp  = (const int*)d_in[9];

    bf16* xb     = (bf16*)d_ws;
    bf16* wqkvb  = xb + (size_t)ROWS * CC;
    bf16* wprojb = wqkvb + (size_t)NQKV * CC;
    bf16* qkvb   = wprojb + (size_t)CC * CC;
    bf16* yb     = xb;   // alias: xb dead after qkv GEMM

    // 1) fused casts: x, Wq, Wk, Wv, Wproj -> contiguous bf16 regions (one launch)
    cast_all<<<18432, 256, 0, stream>>>(x, Wq, Wk, Wv, Wproj, xb);

    // 2) qkv = x @ [Wq;Wk;Wv]^T  (768 blocks = 3/CU, natural order)
    gemm_bt<0><<<dim3(ROWS / 128, NQKV / 128), 256, 0, stream>>>(xb, wqkvb, qkvb, ROWS, NQKV, CC);

    // 3) gate/ve add + RoPE + RMSNorm (in place, BW-bound)
    postproc<<<ROWS, 256, 0, stream>>>(x, ve, cosb, sinb, Wgate, qkvb);

    // 4) MFMA flash attention -> yb
    attn_mfma<<<BB * NHq * (TT / 128), 256, 0, stream>>>(qkvb, yb, winp);

    // 5) out = y @ Wproj^T (fp32 out)
    gemm_bt<1><<<dim3(ROWS / 128, CC / 128), 256, 0, stream>>>(yb, wprojb, d_out, ROWS, CC, CC);
}

// Round 13
// 189.396 us; speedup vs baseline: 1.3303x; 1.1539x over previous
//
#include <hip/hip_runtime.h>
#include <hip/hip_bf16.h>

// Problem constants (reference: B=2, T=2048, C=2048, NH=16, NKV=4, HD=128, GATE_CH=12)
#define BB   2
#define TT   2048
#define CC   2048
#define NHq  16
#define NKVq 4
#define HDq  128
#define ROWS (BB*TT)          // 4096
#define NQKV (NHq*HDq + 2*NKVq*HDq)  // 3072

using bf16 = __hip_bfloat16;
using short8  = __attribute__((ext_vector_type(8))) short;
using short4v = __attribute__((ext_vector_type(4))) short;
using f32x4   = __attribute__((ext_vector_type(4))) float;

#define MFMA16(a,b,c) __builtin_amdgcn_mfma_f32_16x16x32_bf16((a),(b),(c),0,0,0)

// async global->LDS, 16B per lane. LDS dest must be wave-uniform-base + lane*16.
__device__ __forceinline__ void gll16(const bf16* g, void* l) {
    __builtin_amdgcn_global_load_lds((const __attribute__((address_space(1))) void*)g,
                                     (__attribute__((address_space(3))) void*)l,
                                     16, 0, 0);
}

// ---------------- fused cast: all fp32 inputs -> contiguous bf16 ws regions ----------------
// dst layout: [xb 8388608 | wq 4194304 | wk 1048576 | wv 1048576 | wproj 4194304]
__global__ void cast_all(const float* __restrict__ x,  const float* __restrict__ wq,
                         const float* __restrict__ wk, const float* __restrict__ wv,
                         const float* __restrict__ wp, bf16* __restrict__ dst) {
    long e = ((long)blockIdx.x * 256 + threadIdx.x) * 4;
    const float* src; long off;
    if (e < 8388608L)       { src = x;  off = e; }
    else if (e < 12582912L) { src = wq; off = e - 8388608L; }
    else if (e < 13631488L) { src = wk; off = e - 12582912L; }
    else if (e < 14680064L) { src = wv; off = e - 13631488L; }
    else                    { src = wp; off = e - 14680064L; }
    float4 v = *reinterpret_cast<const float4*>(src + off);
    ushort4 o;
    o.x = __bfloat16_as_ushort(__float2bfloat16(v.x));
    o.y = __bfloat16_as_ushort(__float2bfloat16(v.y));
    o.z = __bfloat16_as_ushort(__float2bfloat16(v.z));
    o.w = __bfloat16_as_ushort(__float2bfloat16(v.w));
    *reinterpret_cast<ushort4*>(dst + e) = o;
}

// ---------------- bf16 MFMA GEMM: 128x128 tile, BK=64, XOR-swizzled LDS ----------------
// C[M,N] = A[M,K] * B[N,K]^T. Linear gll16 dest + pre-swizzled global source
// (chunk ^ (row&7), 8x16B chunks per 128B row) + same XOR on ds_read (T21, R9-proven:
// 0 bank conflicts). BK=64 halves barrier-drain pairs vs BK=32 (K=2048: 64->32).
template<int OUT_F32>
__global__ __launch_bounds__(256) void gemm_bt(const bf16* __restrict__ A,
                                               const bf16* __restrict__ B,
                                               void* __restrict__ Cp,
                                               int M, int N, int K) {
    const int bm = blockIdx.x * 128;
    const int bn = blockIdx.y * 128;
    const int tid = threadIdx.x;
    const int lane = tid & 63;
    const int w = tid >> 6;
    const int wr = w >> 1, wc = w & 1;   // 2x2 waves of 64x64

    __shared__ __align__(16) bf16 As[128 * 64];   // 16 KB, swizzled storage
    __shared__ __align__(16) bf16 Bs[128 * 64];   // 16 KB

    f32x4 acc[4][4];
#pragma unroll
    for (int i = 0; i < 4; ++i)
#pragma unroll
        for (int j = 0; j < 4; ++j) acc[i][j] = f32x4{0.f, 0.f, 0.f, 0.f};

    const int srow = tid >> 3;          // 0..31 (+ i*32)
    const int sch  = tid & 7;           // dest 16B chunk

    const int fr = lane & 15;
    const int kq = lane >> 4;           // 0..3

    for (int k0 = 0; k0 < K; k0 += 64) {
        __syncthreads();
#pragma unroll
        for (int i = 0; i < 4; ++i) {
            int row = i * 32 + srow;
            int c = sch ^ (row & 7);    // pre-swizzled source chunk
            gll16(&A[(size_t)(bm + row) * K + k0 + c * 8], (char*)As + i * 4096 + tid * 16);
            gll16(&B[(size_t)(bn + row) * K + k0 + c * 8], (char*)Bs + i * 4096 + tid * 16);
        }
        __syncthreads();

#pragma unroll
        for (int kk = 0; kk < 2; ++kk) {
            short8 af[4], bfr[4];
#pragma unroll
            for (int m = 0; m < 4; ++m) {
                int r = wr * 64 + m * 16 + fr;
                af[m] = *reinterpret_cast<const short8*>(
                    (const char*)As + r * 128 + (((kk * 4 + kq) ^ (r & 7)) * 16));
            }
#pragma unroll
            for (int n = 0; n < 4; ++n) {
                int r = wc * 64 + n * 16 + fr;
                bfr[n] = *reinterpret_cast<const short8*>(
                    (const char*)Bs + r * 128 + (((kk * 4 + kq) ^ (r & 7)) * 16));
            }
            __builtin_amdgcn_s_setprio(1);
#pragma unroll
            for (int m = 0; m < 4; ++m)
#pragma unroll
                for (int n = 0; n < 4; ++n)
                    acc[m][n] = MFMA16(af[m], bfr[n], acc[m][n]);
            __builtin_amdgcn_s_setprio(0);
        }
    }

    const int cr = (lane >> 4) * 4;
    const int cc = lane & 15;
#pragma unroll
    for (int m = 0; m < 4; ++m)
#pragma unroll
        for (int n = 0; n < 4; ++n) {
            int row = bm + wr * 64 + m * 16 + cr;
            int col = bn + wc * 64 + n * 16 + cc;
#pragma unroll
            for (int j = 0; j < 4; ++j) {
                float v = acc[m][n][j];
                if (OUT_F32) ((float*)Cp)[(size_t)(row + j) * N + col] = v;
                else         ((bf16*)Cp)[(size_t)(row + j) * N + col] = __float2bfloat16(v);
            }
        }
}

// ---------------- postproc: gate+ve add on V, RoPE+RMSNorm on Q,K (in place) ----------------
// one block per (b,t) row; qkv row layout: [q 0..2047 | k 2048..2559 | v 2560..3071]
__global__ __launch_bounds__(256) void postproc(const float* __restrict__ x,
                                                const float* __restrict__ ve,
                                                const float* __restrict__ cosb,
                                                const float* __restrict__ sinb,
                                                const float* __restrict__ Wgate,
                                                bf16* __restrict__ qkv) {
    const int row = blockIdx.x;            // b*T + t
    const int t = row & (TT - 1);
    const int tid = threadIdx.x;
    __shared__ float gate_s[NKVq];
    if (tid < NKVq) {
        float g = 0.f;
#pragma unroll
        for (int c = 0; c < 12; ++c) g += x[(size_t)row * CC + c] * Wgate[tid * 12 + c];
        gate_s[tid] = 3.0f / (1.0f + __expf(-g));
    }
    __syncthreads();

    bf16* qkvr = qkv + (size_t)row * NQKV;

#pragma unroll
    for (int i = 0; i < 2; ++i) {
        int idx = tid + i * 256;
        float v = __bfloat162float(qkvr[2560 + idx]);
        v += gate_s[idx >> 7] * ve[(size_t)row * 512 + idx];
        qkvr[2560 + idx] = __float2bfloat16(v);
    }

    const int lane = tid & 63;
    const int w = tid >> 6;
    const float cv = cosb[(size_t)t * 64 + lane];
    const float sv = sinb[(size_t)t * 64 + lane];
    for (int hh = w; hh < NHq + NKVq; hh += 4) {
        int off = (hh < NHq) ? hh * HDq : 2048 + (hh - NHq) * HDq;
        float x1 = __bfloat162float(qkvr[off + lane]);
        float x2 = __bfloat162float(qkvr[off + 64 + lane]);
        float r1 =  x1 * cv + x2 * sv;
        float r2 = -x1 * sv + x2 * cv;
        float ss = r1 * r1 + r2 * r2;
#pragma unroll
        for (int m = 1; m < 64; m <<= 1) ss += __shfl_xor(ss, m);
        float sc = rsqrtf(ss * (1.0f / 128.0f) + 1e-6f) * 1.2f;
        qkvr[off + lane]      = __float2bfloat16(r1 * sc);
        qkvr[off + 64 + lane] = __float2bfloat16(r2 * sc);
    }
}

// ---------------- MFMA flash attention v5 (frozen) ----------------
__global__ __launch_bounds__(256, 2) void attn_mfma(const bf16* __restrict__ qkv,
                                                    bf16* __restrict__ y,
                                                    const int* __restrict__ winp) {
    const int bid = blockIdx.x;
    const int group = bid >> 8, idx = bid & 255;
    const int bh = idx >> 3, jj = idx & 7;
    const int qt = group ? jj : (15 - jj);
    const int h = bh & 15, b = bh >> 4;
    const int t0 = qt * 128;
    const int kvh = h >> 2;
    const int tid = threadIdx.x;
    const int lane = tid & 63;
    const int w = tid >> 6;
    const int window = winp[0];

    __shared__ __align__(16) bf16 Ks[2][64 * 128];
    __shared__ __align__(16) bf16 Vt[128 * 64];
    __shared__ __align__(16) bf16 Ps[4][32 * 64];

    const int fr = lane & 15;
    const int kq = (lane >> 4) * 8;
    const int hi = lane >> 4;

    short8 qf[2][4];
#pragma unroll
    for (int mi = 0; mi < 2; ++mi) {
        const bf16* qp = qkv + ((size_t)(b * TT) + t0 + w * 32 + mi * 16 + fr) * NQKV + h * HDq;
#pragma unroll
        for (int c = 0; c < 4; ++c)
            qf[mi][c] = *reinterpret_cast<const short8*>(&qp[c * 32 + kq]);
    }

    f32x4 acc[2][8];
#pragma unroll
    for (int mi = 0; mi < 2; ++mi)
#pragma unroll
        for (int n = 0; n < 8; ++n) acc[mi][n] = f32x4{0.f, 0.f, 0.f, 0.f};
    float m2[2][4], lrow[2][4];
#pragma unroll
    for (int mi = 0; mi < 2; ++mi)
#pragma unroll
        for (int j = 0; j < 4; ++j) { m2[mi][j] = -1e30f; lrow[mi][j] = 0.f; }

    int s_lo = t0 - window; if (s_lo < 0) s_lo = 0; s_lo &= ~63;
    const int s_end = t0 + 128;

    const bf16* Kg = qkv + (size_t)b * TT * NQKV + 2048 + kvh * HDq;
    const bf16* Vg = Kg + 512;

    const int str = tid >> 4;
    const int sti = tid & 15;
    const int vf  = tid & 15;
    const int vdc = (tid >> 4) * 8;
    const float scl2 = 0.08838834764831845f * 1.4426950408889634f;
    const float THR2 = 11.54f;

    short8 vr[4];

#pragma unroll
    for (int p = 0; p < 4; ++p) {
        int row = p * 16 + str;
        int c16 = sti ^ (row & 7);
        gll16(&Kg[(size_t)(s_lo + row) * NQKV + c16 * 8], (char*)Ks + p * 4096 + tid * 16);
    }
#pragma unroll
    for (int i = 0; i < 4; ++i)
        vr[i] = *reinterpret_cast<const short8*>(&Vg[(size_t)(s_lo + 16 * i + vf) * NQKV + vdc]);
#pragma unroll
    for (int j = 0; j < 8; ++j) {
        short4v col;
        col[0] = vr[0][j]; col[1] = vr[1][j]; col[2] = vr[2][j]; col[3] = vr[3][j];
        *reinterpret_cast<short4v*>((char*)Vt + (vdc + j) * 128 + ((8 * vf) ^ (j << 4))) = col;
    }
    __syncthreads();

    int cur = 0;
    for (int sk = s_lo; sk < s_end; sk += 64) {
        const bool hn = (sk + 64 < s_end);
        if (hn) {
#pragma unroll
            for (int p = 0; p < 4; ++p) {
                int row = p * 16 + str;
                int c16 = sti ^ (row & 7);
                gll16(&Kg[(size_t)(sk + 64 + row) * NQKV + c16 * 8],
                      (char*)Ks + (cur ^ 1) * 16384 + p * 4096 + tid * 16);
            }
#pragma unroll
            for (int i = 0; i < 4; ++i)
                vr[i] = *reinterpret_cast<const short8*>(&Vg[(size_t)(sk + 64 + 16 * i + vf) * NQKV + vdc]);
        }

        f32x4 S[2][4];
#pragma unroll
        for (int mi = 0; mi < 2; ++mi)
#pragma unroll
            for (int n = 0; n < 4; ++n) S[mi][n] = f32x4{0.f, 0.f, 0.f, 0.f};
        __builtin_amdgcn_s_setprio(1);
#pragma unroll
        for (int n = 0; n < 4; ++n) {
            int rb = n * 16 + fr;
#pragma unroll
            for (int c = 0; c < 4; ++c) {
                int colb = c * 64 + kq * 2;
                short8 kf = *reinterpret_cast<const short8*>(
                    (const char*)Ks + cur * 16384 + rb * 256 + (colb ^ ((rb & 7) << 4)));
                S[0][n] = MFMA16(qf[0][c], kf, S[0][n]);
                S[1][n] = MFMA16(qf[1][c], kf, S[1][n]);
            }
        }
        __builtin_amdgcn_s_setprio(0);

        const int rw0 = t0 + w * 32;
        const bool interior = (sk + 63 <= rw0) && (rw0 + 31 - sk <= window);
#pragma unroll
        for (int mi = 0; mi < 2; ++mi) {
#pragma unroll
            for (int j = 0; j < 4; ++j) {
                const int rl = hi * 4 + j;
                float s0, s1, s2, s3;
                if (interior) {
                    s0 = S[mi][0][j] * scl2; s1 = S[mi][1][j] * scl2;
                    s2 = S[mi][2][j] * scl2; s3 = S[mi][3][j] * scl2;
                } else {
                    const int r = rw0 + mi * 16 + rl;
                    int c0 = sk + fr, c1 = c0 + 16, c2 = c0 + 32, c3 = c0 + 48;
                    s0 = (c0 <= r && r - c0 <= window) ? S[mi][0][j] * scl2 : -1e30f;
                    s1 = (c1 <= r && r - c1 <= window) ? S[mi][1][j] * scl2 : -1e30f;
                    s2 = (c2 <= r && r - c2 <= window) ? S[mi][2][j] * scl2 : -1e30f;
                    s3 = (c3 <= r && r - c3 <= window) ? S[mi][3][j] * scl2 : -1e30f;
                }
                float pm = fmaxf(fmaxf(s0, s1), fmaxf(s2, s3));
                if (!__all(pm <= m2[mi][j] + THR2)) {
                    float pr = pm;
#pragma unroll
                    for (int mm = 1; mm < 16; mm <<= 1) pr = fmaxf(pr, __shfl_xor(pr, mm));
                    float nm = fmaxf(m2[mi][j], pr);
                    float corr = exp2f(m2[mi][j] - nm);
                    m2[mi][j] = nm;
                    lrow[mi][j] *= corr;
#pragma unroll
                    for (int n = 0; n < 8; ++n) acc[mi][n][j] *= corr;
                }
                float p0 = exp2f(s0 - m2[mi][j]);
                float p1 = exp2f(s1 - m2[mi][j]);
                float p2 = exp2f(s2 - m2[mi][j]);
                float p3 = exp2f(s3 - m2[mi][j]);
                if (!interior) {
                    p0 = (s0 > -1e29f) ? p0 : 0.f;
                    p1 = (s1 > -1e29f) ? p1 : 0.f;
                    p2 = (s2 > -1e29f) ? p2 : 0.f;
                    p3 = (s3 > -1e29f) ? p3 : 0.f;
                }
                lrow[mi][j] += (p0 + p1) + (p2 + p3);
                short4v pk;
                pk[0] = (short)__bfloat16_as_ushort(__float2bfloat16(p0));
                pk[1] = (short)__bfloat16_as_ushort(__float2bfloat16(p1));
                pk[2] = (short)__bfloat16_as_ushort(__float2bfloat16(p2));
                pk[3] = (short)__bfloat16_as_ushort(__float2bfloat16(p3));
                const int prow = mi * 16 + rl;
                *reinterpret_cast<short4v*>(
                    (char*)Ps + w * 4096 + prow * 128 + ((8 * fr) ^ ((prow & 7) << 4))) = pk;
            }
        }

        __builtin_amdgcn_s_setprio(1);
#pragma unroll
        for (int c2 = 0; c2 < 2; ++c2) {
            short8 pa0 = *reinterpret_cast<const short8*>(
                (char*)Ps + w * 4096 + fr * 128 + ((c2 * 64 + hi * 16) ^ ((fr & 7) << 4)));
            short8 pa1 = *reinterpret_cast<const short8*>(
                (char*)Ps + w * 4096 + (16 + fr) * 128 + ((c2 * 64 + hi * 16) ^ ((fr & 7) << 4)));
#pragma unroll
            for (int n = 0; n < 8; ++n) {
                short8 vb = *reinterpret_cast<const short8*>(
                    (char*)Vt + (n * 16 + fr) * 128 + ((c2 * 64 + hi * 16) ^ ((fr & 7) << 4)));
                acc[0][n] = MFMA16(pa0, vb, acc[0][n]);
                acc[1][n] = MFMA16(pa1, vb, acc[1][n]);
            }
        }
        __builtin_amdgcn_s_setprio(0);

        __syncthreads();
        if (hn) {
#pragma unroll
            for (int j = 0; j < 8; ++j) {
                short4v col;
                col[0] = vr[0][j]; col[1] = vr[1][j]; col[2] = vr[2][j]; col[3] = vr[3][j];
                *reinterpret_cast<short4v*>((char*)Vt + (vdc + j) * 128 + ((8 * vf) ^ (j << 4))) = col;
            }
        }
        __syncthreads();
        cur ^= 1;
    }

#pragma unroll
    for (int mi = 0; mi < 2; ++mi)
#pragma unroll
        for (int j = 0; j < 4; ++j) {
            float l = lrow[mi][j];
#pragma unroll
            for (int mm = 1; mm < 16; mm <<= 1) l += __shfl_xor(l, mm);
            const int r = t0 + w * 32 + mi * 16 + hi * 4 + j;
            float inv = 1.f / l;
            bf16* yr = y + ((size_t)(b * TT) + r) * CC + h * HDq;
#pragma unroll
            for (int n = 0; n < 8; ++n)
                yr[n * 16 + fr] = __float2bfloat16(acc[mi][n][j] * inv);
        }
}

extern "C" void kernel_launch(void* const* d_in, const int* in_sizes, int n_in,
                              void* d_out, int out_size, void* d_ws, size_t ws_size,
                              hipStream_t stream) {
    const float* x     = (const float*)d_in[0];
    const float* ve    = (const float*)d_in[1];
    const float* cosb  = (const float*)d_in[2];
    const float* sinb  = (const float*)d_in[3];
    const float* Wq    = (const float*)d_in[4];
    const float* Wk    = (const float*)d_in[5];
    const float* Wv    = (const float*)d_in[6];
    const float* Wproj = (const float*)d_in[7];
    const float* Wgate = (const float*)d_in[8];
    const int*   winp  = (const int*)d_in[9];

    bf16* xb     = (bf16*)d_ws;
    bf16* wqkvb  = xb + (size_t)ROWS * CC;
    bf16* wprojb = wqkvb + (size_t)NQKV * CC;
    bf16* qkvb   = wprojb + (size_t)CC * CC;
    bf16* yb     = xb;   // alias: xb dead after qkv GEMM

    // 1) fused casts: x, Wq, Wk, Wv, Wproj -> contiguous bf16 regions (one launch)
    cast_all<<<18432, 256, 0, stream>>>(x, Wq, Wk, Wv, Wproj, xb);

    // 2) qkv = x @ [Wq;Wk;Wv]^T  (768 blocks = 3/CU, natural order, BK=64 swizzled)
    gemm_bt<0><<<dim3(ROWS / 128, NQKV / 128), 256, 0, stream>>>(xb, wqkvb, qkvb, ROWS, NQKV, CC);

    // 3) gate/ve add + RoPE + RMSNorm (in place, BW-bound)
    postproc<<<ROWS, 256, 0, stream>>>(x, ve, cosb, sinb, Wgate, qkvb);

    // 4) MFMA flash attention -> yb
    attn_mfma<<<BB * NHq * (TT / 128), 256, 0, stream>>>(qkvb, yb, winp);

    // 5) out = y @ Wproj^T (fp32 out)
    gemm_bt<1><<<dim3(ROWS / 128, CC / 128), 256, 0, stream>>>(yb, wprojb, d_out, ROWS, CC, CC);
}